// Round 5
// baseline (437.417 us; speedup 1.0000x reference)
//
#include <hip/hip_runtime.h>
#include <math.h>

typedef __bf16 bf16x8 __attribute__((ext_vector_type(8)));
typedef float f32x4 __attribute__((ext_vector_type(4)));
typedef unsigned short ushort_t;

#define SEQ 2048
#define MROWS 4096          // B*S
#define EPS 1e-5f
#define KST 72              // flash LDS row stride (elements): 144B, bank-rotating
#define LOG2E 1.4426950408889634f

#if __has_builtin(__builtin_amdgcn_exp2f)
#define EXP2(x) __builtin_amdgcn_exp2f(x)
#else
#define EXP2(x) exp2f(x)
#endif

// ---------- bf16 helpers ----------
__device__ __forceinline__ float bf2f(ushort_t u) {
  union { unsigned int i; float f; } c; c.i = ((unsigned int)u) << 16; return c.f;
}
__device__ __forceinline__ ushort_t f2bf(float f) {   // native RNE cvt
  __bf16 h = (__bf16)f;
  union { __bf16 b; ushort_t u; } c; c.b = h; return c.u;
}

// ---------- reductions ----------
__device__ __forceinline__ float wave_sum(float v) {
  #pragma unroll
  for (int off = 32; off > 0; off >>= 1) v += __shfl_xor(v, off);
  return v;
}

// ---------- 0a. dtype detector: is x bf16 (1) or fp32 (0)? ----------
__global__ void detect_kernel(const unsigned int* __restrict__ xraw, int* __restrict__ flag) {
  int tid = threadIdx.x;
  int cnt = 0;
  for (int i = tid; i < 4096; i += 256) {
    unsigned int e = (xraw[i] >> 7) & 0xFFu;
    cnt += (e >= 100u && e <= 150u) ? 1 : 0;
  }
  __shared__ int sred[256];
  sred[tid] = cnt;
  __syncthreads();
  for (int s = 128; s > 0; s >>= 1) {
    if (tid < s) sred[tid] += sred[tid + s];
    __syncthreads();
  }
  if (tid == 0) flag[0] = (sred[0] > 2048) ? 1 : 0;
}

// ---------- 0b. canonicalize ----------
__global__ void conv_f32(const void* __restrict__ in, float* __restrict__ outp,
                         int n, const int* __restrict__ flag) {
  int i = blockIdx.x * 256 + threadIdx.x;
  if (i >= n) return;
  if (*flag) outp[i] = bf2f(((const ushort_t*)in)[i]);
  else       outp[i] = ((const float*)in)[i];
}
__global__ void conv_b16(const void* __restrict__ in, ushort_t* __restrict__ outp,
                         int n, const int* __restrict__ flag) {
  int i = blockIdx.x * 256 + threadIdx.x;
  if (i >= n) return;
  if (*flag) outp[i] = ((const ushort_t*)in)[i];
  else       outp[i] = f2bf(((const float*)in)[i]);
}

// ---------- 1. prenorm RMSNorm (raw x per flag -> bf16 xn) ----------
__global__ void prenorm_kernel(const void* __restrict__ xraw,
                               const float* __restrict__ w,
                               ushort_t* __restrict__ xn,
                               const int* __restrict__ flag) {
  int row = blockIdx.x;
  int tid = threadIdx.x;
  float4 u;
  if (*flag) {
    ushort4 s = ((const ushort4*)xraw)[row * 256 + tid];
    u.x = bf2f(s.x); u.y = bf2f(s.y); u.z = bf2f(s.z); u.w = bf2f(s.w);
  } else {
    u = ((const float4*)xraw)[row * 256 + tid];
  }
  float ss = u.x*u.x + u.y*u.y + u.z*u.z + u.w*u.w;
  ss = wave_sum(ss);
  __shared__ float red[4];
  if ((tid & 63) == 0) red[tid >> 6] = ss;
  __syncthreads();
  float total = red[0] + red[1] + red[2] + red[3];
  float inv = rsqrtf(total * (1.0f / 1024.0f) + EPS);
  float4 wu = ((const float4*)w)[tid];
  ushort4 o;
  o.x = f2bf(u.x * inv * wu.x);
  o.y = f2bf(u.y * inv * wu.y);
  o.z = f2bf(u.z * inv * wu.z);
  o.w = f2bf(u.w * inv * wu.w);
  ((ushort4*)(xn + (long long)row * 1024))[tid] = o;
}

// ---------- 2. tiled bf16 GEMM (m97 structure): C[m][n]=sum_k A[m][k]B[n][k] ----------
// 128x128 tile, 4 waves 2x2 (64x64 each), BK=32, global_load_lds staging.
// res/out dtype dispatched on *flag (res may be null; flag may be null -> bf16 out).
__device__ __forceinline__ void gll16(const ushort_t* g, ushort_t* l) {
  __builtin_amdgcn_global_load_lds(
      (const __attribute__((address_space(1))) unsigned int*)g,
      (__attribute__((address_space(3))) unsigned int*)l, 16, 0, 0);
}
__global__ void gemm_tiled(const ushort_t* __restrict__ A, const ushort_t* __restrict__ B,
                           void* __restrict__ Cv, const void* __restrict__ res,
                           const int* __restrict__ flag,
                           int K, int lda, int ldb, int ldc) {
  __shared__ ushort_t As[128 * 32];
  __shared__ ushort_t Bs[128 * 32];
  int tid = threadIdx.x, wave = tid >> 6, lane = tid & 63;
  int m_blk = blockIdx.y * 128, n_blk = blockIdx.x * 128;
  int wm = (wave & 1) * 64, wn = (wave >> 1) * 64;
  int g = lane >> 4, c = lane & 15;
  int arow = lane >> 2;
  int akc = (lane & 3) << 3;
  f32x4 acc[4][4] = {};
  for (int kt = 0; kt < K; kt += 32) {
    #pragma unroll
    for (int i = 0; i < 2; ++i) {
      int rbase = (i * 4 + wave) * 16;
      gll16(A + (long long)(m_blk + rbase + arow) * lda + kt + akc, &As[rbase * 32]);
      gll16(B + (long long)(n_blk + rbase + arow) * ldb + kt + akc, &Bs[rbase * 32]);
    }
    __syncthreads();
    bf16x8 af[4], bfr[4];
    #pragma unroll
    for (int mi = 0; mi < 4; ++mi)
      af[mi] = *(const bf16x8*)&As[(wm + mi * 16 + c) * 32 + (g << 3)];
    #pragma unroll
    for (int ni = 0; ni < 4; ++ni)
      bfr[ni] = *(const bf16x8*)&Bs[(wn + ni * 16 + c) * 32 + (g << 3)];
    #pragma unroll
    for (int mi = 0; mi < 4; ++mi)
      #pragma unroll
      for (int ni = 0; ni < 4; ++ni)
        acc[mi][ni] = __builtin_amdgcn_mfma_f32_16x16x32_bf16(af[mi], bfr[ni], acc[mi][ni], 0, 0, 0);
    __syncthreads();
  }
  int outbf = flag ? *flag : 1;
  #pragma unroll
  for (int mi = 0; mi < 4; ++mi)
    #pragma unroll
    for (int ni = 0; ni < 4; ++ni)
      #pragma unroll
      for (int r = 0; r < 4; ++r) {
        int row = m_blk + wm + mi * 16 + g * 4 + r;
        int col = n_blk + wn + ni * 16 + c;
        long long idx = (long long)row * ldc + col;
        float v = acc[mi][ni][r];
        if (res) v += outbf ? bf2f(((const ushort_t*)res)[idx]) : ((const float*)res)[idx];
        if (outbf) ((ushort_t*)Cv)[idx] = f2bf(v);
        else       ((float*)Cv)[idx] = v;
      }
}

// ---------- 2b. gate GEMM (bf16 in, fp32 SIGMOID out), N=16 ----------
__global__ void gate_gemm(const ushort_t* __restrict__ A, const ushort_t* __restrict__ B,
                          float* __restrict__ C) {
  int lane = threadIdx.x & 63;
  int wave = threadIdx.x >> 6;
  int m0 = (blockIdx.y * 4 + wave) * 16;
  const ushort_t* Ap = A + (long long)(m0 + (lane & 15)) * 1024 + ((lane >> 4) << 3);
  const ushort_t* Bp = B + (long long)(lane & 15) * 1024 + ((lane >> 4) << 3);
  f32x4 acc = {0.f, 0.f, 0.f, 0.f};
  for (int k = 0; k < 1024; k += 32) {
    bf16x8 a = *(const bf16x8*)(Ap + k);
    bf16x8 b = *(const bf16x8*)(Bp + k);
    acc = __builtin_amdgcn_mfma_f32_16x16x32_bf16(a, b, acc, 0, 0, 0);
  }
  int col = lane & 15;
  int row0 = m0 + ((lane >> 4) << 2);
  #pragma unroll
  for (int r = 0; r < 4; ++r)
    C[(long long)(row0 + r) * 16 + col] = 1.0f / (1.0f + __expf(-acc[r]));
}

// ---------- 3. q/k per-head RMSNorm; q gets 0.125*log2(e) folded in ----------
__global__ void qk_norm_kernel(ushort_t* __restrict__ qkv,
                               const float* __restrict__ qw, const float* __restrict__ kw) {
  int wid = blockIdx.x * 4 + (threadIdx.x >> 6);
  int lane = threadIdx.x & 63;
  int head = wid & 15;
  int isk = (wid >> 4) & 1;
  int row = wid >> 5;
  ushort_t* p = qkv + (long long)row * 3072 + isk * 1024 + head * 64 + lane;
  float v = bf2f(*p);
  float ss = wave_sum(v * v);
  float inv = rsqrtf(ss * (1.0f / 64.0f) + EPS);
  float w = isk ? kw[lane] : qw[lane];
  float scale = isk ? 1.0f : (0.125f * LOG2E);   // softmax runs base-2
  *p = f2bf(v * inv * w * scale);
}

// ---------- 4. V transpose (bf16): Vt[bh][d][s] = qkv[b][s][2048+h*64+d] ----------
__global__ void vt_kernel(const ushort_t* __restrict__ qkv, ushort_t* __restrict__ Vt) {
  __shared__ ushort_t tile[64][65];
  int s0 = blockIdx.x * 64;
  int bh = blockIdx.y;
  int b = bh >> 4, h = bh & 15;
  const ushort_t* src = qkv + (long long)b * SEQ * 3072 + 2048 + h * 64;
  int d = threadIdx.x & 63, srow = threadIdx.x >> 6;
  #pragma unroll
  for (int i = 0; i < 16; ++i) {
    int sl = i * 4 + srow;
    tile[sl][d] = src[(long long)(s0 + sl) * 3072 + d];
  }
  __syncthreads();
  ushort_t* dst = Vt + (long long)bh * 64 * SEQ + s0;
  int sl2 = threadIdx.x & 63, drow = threadIdx.x >> 6;
  #pragma unroll
  for (int i = 0; i < 16; ++i) {
    int dd = i * 4 + drow;
    dst[(long long)dd * SEQ + sl2] = tile[sl2][dd];
  }
}

// ---------- 5. flash attention, conflict-free LDS (stride 72), fused gate ----------
// grid (SEQ/64, 32). Q-tile 64 (16 rows/wave), KV-tile 64, online softmax (base 2).
__global__ void flash_kernel(const ushort_t* __restrict__ qkv, const ushort_t* __restrict__ Vt,
                             const float* __restrict__ gate, ushort_t* __restrict__ ao) {
  __shared__ ushort_t Ks[64 * KST];
  __shared__ ushort_t Vs[64 * KST];
  __shared__ ushort_t Ps[4][16 * KST];
  int tid = threadIdx.x, wave = tid >> 6, lane = tid & 63;
  int g = lane >> 4, c = lane & 15;
  int q0 = blockIdx.x * 64;
  int bh = blockIdx.y, b = bh >> 4, h = bh & 15;
  const ushort_t* qbase = qkv + (long long)b * SEQ * 3072 + h * 64;
  const ushort_t* kbase = qbase + 1024;
  const ushort_t* vtbase = Vt + (long long)bh * 64 * SEQ;
  int qrow = q0 + wave * 16 + c;
  bf16x8 qa0 = *(const bf16x8*)(qbase + (long long)qrow * 3072 + (g << 3));
  bf16x8 qa1 = *(const bf16x8*)(qbase + (long long)qrow * 3072 + 32 + (g << 3));
  f32x4 accO[4] = {};
  float m_i[4] = {-1e30f, -1e30f, -1e30f, -1e30f};
  float l_i[4] = {0.f, 0.f, 0.f, 0.f};
  int srow = tid >> 3;            // 0..31
  int sch = (tid & 7) << 3;       // 0,8,..,56 (elements)
  // prefetch tile 0 into registers
  uint4 pk[2], pv[2];
  #pragma unroll
  for (int t = 0; t < 2; ++t) {
    int row = t * 32 + srow;
    pk[t] = *(const uint4*)(kbase + (long long)row * 3072 + sch);
    pv[t] = *(const uint4*)(vtbase + (long long)row * SEQ + sch);
  }
  for (int s0 = 0; s0 < SEQ; s0 += 64) {
    // store staged tile (conflict-free: bank = 4*((row+ch)&7))
    #pragma unroll
    for (int t = 0; t < 2; ++t) {
      int row = t * 32 + srow;
      *(uint4*)&Ks[row * KST + sch] = pk[t];
      *(uint4*)&Vs[row * KST + sch] = pv[t];
    }
    // prefetch next tile (latency hidden behind compute below)
    if (s0 + 64 < SEQ) {
      #pragma unroll
      for (int t = 0; t < 2; ++t) {
        int row = t * 32 + srow;
        pk[t] = *(const uint4*)(kbase + (long long)(s0 + 64 + row) * 3072 + sch);
        pv[t] = *(const uint4*)(vtbase + (long long)row * SEQ + s0 + 64 + sch);
      }
    }
    __syncthreads();
    // S = q.k^T (C-layout), conflict-free reads
    f32x4 sacc[4] = {};
    #pragma unroll
    for (int ni = 0; ni < 4; ++ni) {
      bf16x8 kb0 = *(const bf16x8*)&Ks[(ni * 16 + c) * KST + (g << 3)];
      bf16x8 kb1 = *(const bf16x8*)&Ks[(ni * 16 + c) * KST + 32 + (g << 3)];
      sacc[ni] = __builtin_amdgcn_mfma_f32_16x16x32_bf16(qa0, kb0, sacc[ni], 0, 0, 0);
      sacc[ni] = __builtin_amdgcn_mfma_f32_16x16x32_bf16(qa1, kb1, sacc[ni], 0, 0, 0);
    }
    // online softmax (base-2; scale folded into q)
    float alpha[4];
    #pragma unroll
    for (int r = 0; r < 4; ++r) {
      float mx = fmaxf(fmaxf(sacc[0][r], sacc[1][r]), fmaxf(sacc[2][r], sacc[3][r]));
      #pragma unroll
      for (int off = 8; off > 0; off >>= 1) mx = fmaxf(mx, __shfl_xor(mx, off));
      float mn = fmaxf(m_i[r], mx);
      alpha[r] = EXP2(m_i[r] - mn);
      m_i[r] = mn;
      float rs = 0.f;
      #pragma unroll
      for (int ni = 0; ni < 4; ++ni) {
        float p = EXP2(sacc[ni][r] - mn);
        rs += p;
        Ps[wave][(g * 4 + r) * KST + ni * 16 + c] = f2bf(p);
      }
      #pragma unroll
      for (int off = 8; off > 0; off >>= 1) rs += __shfl_xor(rs, off);
      l_i[r] = l_i[r] * alpha[r] + rs;
    }
    #pragma unroll
    for (int di = 0; di < 4; ++di)
      #pragma unroll
      for (int r = 0; r < 4; ++r) accO[di][r] *= alpha[r];
    bf16x8 pa0 = *(const bf16x8*)&Ps[wave][c * KST + (g << 3)];
    bf16x8 pa1 = *(const bf16x8*)&Ps[wave][c * KST + 32 + (g << 3)];
    #pragma unroll
    for (int di = 0; di < 4; ++di) {
      bf16x8 vb0 = *(const bf16x8*)&Vs[(di * 16 + c) * KST + (g << 3)];
      bf16x8 vb1 = *(const bf16x8*)&Vs[(di * 16 + c) * KST + 32 + (g << 3)];
      accO[di] = __builtin_amdgcn_mfma_f32_16x16x32_bf16(pa0, vb0, accO[di], 0, 0, 0);
      accO[di] = __builtin_amdgcn_mfma_f32_16x16x32_bf16(pa1, vb1, accO[di], 0, 0, 0);
    }
    __syncthreads();
  }
  // epilogue: O * sigmoid(gate) / l -> ao
  #pragma unroll
  for (int r = 0; r < 4; ++r) {
    int row = q0 + wave * 16 + g * 4 + r;
    float sg = gate[(long long)(b * SEQ + row) * 16 + h];  // pre-sigmoided
    float scale = sg / l_i[r];
    #pragma unroll
    for (int di = 0; di < 4; ++di) {
      int col = h * 64 + di * 16 + c;
      ao[(long long)(b * SEQ + row) * 1024 + col] = f2bf(accO[di][r] * scale);
    }
  }
}

extern "C" void kernel_launch(void* const* d_in, const int* in_sizes, int n_in,
                              void* d_out, int out_size, void* d_ws, size_t ws_size,
                              hipStream_t stream) {
  (void)in_sizes; (void)n_in; (void)out_size; (void)ws_size;
  char* ws = (char*)d_ws;
  ushort_t* qkvw = (ushort_t*)(ws);                             // 6 MB bf16 3072x1024
  ushort_t* ow   = (ushort_t*)(ws + (6ll << 20));               // 2 MB bf16 1024x1024
  ushort_t* gw   = (ushort_t*)(ws + (8ll << 20));               // 32 KB bf16 16x1024
  float*    pwf  = (float*)   (ws + (8ll << 20) + (64 << 10));  // 4 KB
  float*    qnf  = (float*)   (ws + (8ll << 20) + (72 << 10));
  float*    knf  = (float*)   (ws + (8ll << 20) + (76 << 10));
  int*      flag = (int*)     (ws + (8ll << 20) + (80 << 10));
  float*    gate = (float*)   (ws + (8ll << 20) + (128 << 10)); // 256 KB fp32 (sigmoided)
  ushort_t* xn   = (ushort_t*)(ws + (9ll << 20));               // 8 MB bf16 4096x1024
  ushort_t* qkv  = (ushort_t*)(ws + (17ll << 20));              // 24 MB bf16 4096x3072
  ushort_t* Vt   = (ushort_t*)(ws + (41ll << 20));              // 8 MB bf16 32x64x2048
  ushort_t* ao   = (ushort_t*)(ws + (49ll << 20));              // 8 MB bf16 4096x1024

  // 0. detect + canonicalize (weights only; x stays raw)
  detect_kernel<<<1, 256, 0, stream>>>((const unsigned int*)d_in[0], flag);
  conv_f32<<<4, 256, 0, stream>>>(d_in[1], pwf, 1024, flag);
  conv_b16<<<12288, 256, 0, stream>>>(d_in[2], qkvw, 3145728, flag);
  conv_b16<<<64, 256, 0, stream>>>(d_in[3], gw, 16384, flag);
  conv_b16<<<4096, 256, 0, stream>>>(d_in[4], ow, 1048576, flag);
  conv_f32<<<1, 256, 0, stream>>>(d_in[5], qnf, 64, flag);
  conv_f32<<<1, 256, 0, stream>>>(d_in[6], knf, 64, flag);

  // 1. prenorm (raw x -> bf16 xn)
  prenorm_kernel<<<MROWS, 256, 0, stream>>>(d_in[0], pwf, xn, flag);
  // 2. qkv = xn @ qkv_w^T  (M=4096,N=3072,K=1024)
  gemm_tiled<<<dim3(24, 32), 256, 0, stream>>>(xn, qkvw, qkv, nullptr, nullptr,
                                               1024, 1024, 1024, 3072);
  // 2b. gate (with fused sigmoid)
  gate_gemm<<<dim3(1, 64), 256, 0, stream>>>(xn, gw, gate);
  // 3. q/k RMSNorm (+ q *= 0.125*log2e)
  qk_norm_kernel<<<32768, 256, 0, stream>>>(qkv, qnf, knf);
  // 4. V transpose
  vt_kernel<<<dim3(32, 32), 256, 0, stream>>>(qkv, Vt);
  // 5. flash attention (fused gate multiply)
  flash_kernel<<<dim3(32, 32), 256, 0, stream>>>(qkv, Vt, gate, ao);
  // 6. out = ao @ o_w^T + x (raw residual), dtype-dispatched store
  gemm_tiled<<<dim3(8, 32), 256, 0, stream>>>(ao, ow, d_out, d_in[0], flag,
                                              1024, 1024, 1024, 1024);
}

// Round 6
// 425.653 us; speedup vs baseline: 1.0276x; 1.0276x over previous
//
#include <hip/hip_runtime.h>
#include <math.h>

typedef __bf16 bf16x8 __attribute__((ext_vector_type(8)));
typedef float f32x4 __attribute__((ext_vector_type(4)));
typedef unsigned short ushort_t;

#define SEQ 2048
#define MROWS 4096          // B*S
#define EPS 1e-5f
#define KST 72              // flash LDS row stride (elements): 144B, bank-rotating
#define QKS 3200            // fused qkv output row stride (q 0..1023, k 1024.., v 2048.., gate 3072..3087, pad)
#define LOG2E 1.4426950408889634f

#if __has_builtin(__builtin_amdgcn_exp2f)
#define EXP2(x) __builtin_amdgcn_exp2f(x)
#else
#define EXP2(x) exp2f(x)
#endif

// ---------- bf16 helpers ----------
__device__ __forceinline__ float bf2f(ushort_t u) {
  union { unsigned int i; float f; } c; c.i = ((unsigned int)u) << 16; return c.f;
}
__device__ __forceinline__ ushort_t f2bf(float f) {
  __bf16 h = (__bf16)f;
  union { __bf16 b; ushort_t u; } c; c.b = h; return c.u;
}

// ---------- reductions ----------
__device__ __forceinline__ float wave_sum(float v) {
  #pragma unroll
  for (int off = 32; off > 0; off >>= 1) v += __shfl_xor(v, off);
  return v;
}

// ---------- 0a. dtype detector: is x bf16 (1) or fp32 (0)? ----------
__global__ void detect_kernel(const unsigned int* __restrict__ xraw, int* __restrict__ flag) {
  int tid = threadIdx.x;
  int cnt = 0;
  for (int i = tid; i < 4096; i += 256) {
    unsigned int e = (xraw[i] >> 7) & 0xFFu;
    cnt += (e >= 100u && e <= 150u) ? 1 : 0;
  }
  __shared__ int sred[256];
  sred[tid] = cnt;
  __syncthreads();
  for (int s = 128; s > 0; s >>= 1) {
    if (tid < s) sred[tid] += sred[tid + s];
    __syncthreads();
  }
  if (tid == 0) flag[0] = (sred[0] > 2048) ? 1 : 0;
}

// ---------- 0b. canonicalize ----------
__global__ void conv_f32(const void* __restrict__ in, float* __restrict__ outp,
                         int n, const int* __restrict__ flag) {
  int i = blockIdx.x * 256 + threadIdx.x;
  if (i >= n) return;
  if (*flag) outp[i] = bf2f(((const ushort_t*)in)[i]);
  else       outp[i] = ((const float*)in)[i];
}
__global__ void conv_b16(const void* __restrict__ in, ushort_t* __restrict__ outp,
                         int n, const int* __restrict__ flag) {
  int i = blockIdx.x * 256 + threadIdx.x;
  if (i >= n) return;
  if (*flag) outp[i] = ((const ushort_t*)in)[i];
  else       outp[i] = f2bf(((const float*)in)[i]);
}

// ---------- 1. prenorm RMSNorm (raw x per flag -> bf16 xn) ----------
__global__ void prenorm_kernel(const void* __restrict__ xraw,
                               const float* __restrict__ w,
                               ushort_t* __restrict__ xn,
                               const int* __restrict__ flag) {
  int row = blockIdx.x;
  int tid = threadIdx.x;
  float4 u;
  if (*flag) {
    ushort4 s = ((const ushort4*)xraw)[row * 256 + tid];
    u.x = bf2f(s.x); u.y = bf2f(s.y); u.z = bf2f(s.z); u.w = bf2f(s.w);
  } else {
    u = ((const float4*)xraw)[row * 256 + tid];
  }
  float ss = u.x*u.x + u.y*u.y + u.z*u.z + u.w*u.w;
  ss = wave_sum(ss);
  __shared__ float red[4];
  if ((tid & 63) == 0) red[tid >> 6] = ss;
  __syncthreads();
  float total = red[0] + red[1] + red[2] + red[3];
  float inv = rsqrtf(total * (1.0f / 1024.0f) + EPS);
  float4 wu = ((const float4*)w)[tid];
  ushort4 o;
  o.x = f2bf(u.x * inv * wu.x);
  o.y = f2bf(u.y * inv * wu.y);
  o.z = f2bf(u.z * inv * wu.z);
  o.w = f2bf(u.w * inv * wu.w);
  ((ushort4*)(xn + (long long)row * 1024))[tid] = o;
}

// ---------- async global->LDS 16B ----------
__device__ __forceinline__ void gll16(const ushort_t* g, ushort_t* l) {
  __builtin_amdgcn_global_load_lds(
      (const __attribute__((address_space(1))) unsigned int*)g,
      (__attribute__((address_space(3))) unsigned int*)l, 16, 0, 0);
}

// ---------- 2. fused qkv+gate GEMM, 128x128 tile (m97 structure) ----------
// A = xn (4096x1024), B = Wcat (3200x1024: qkv_w rows 0..3071, gate_w 3072..3087, pad).
// Epilogue: cols<2048 -> per-head RMSNorm (+0.125*log2e on q); <3072 -> plain V;
// ==3072 tile ni==0 -> sigmoid gate (fp32); else skip.
__global__ void gemm_qkv_fused(const ushort_t* __restrict__ A, const ushort_t* __restrict__ B,
                               ushort_t* __restrict__ C, float* __restrict__ gate,
                               const float* __restrict__ qw, const float* __restrict__ kw) {
  __shared__ ushort_t As[128 * 32];
  __shared__ ushort_t Bs[128 * 32];
  int tid = threadIdx.x, wave = tid >> 6, lane = tid & 63;
  int m_blk = blockIdx.y * 128, n_blk = blockIdx.x * 128;
  int wm = (wave & 1) * 64, wn = (wave >> 1) * 64;
  int g = lane >> 4, c = lane & 15;
  int arow = lane >> 2;
  int akc = (lane & 3) << 3;
  f32x4 acc[4][4] = {};
  for (int kt = 0; kt < 1024; kt += 32) {
    #pragma unroll
    for (int i = 0; i < 2; ++i) {
      int rbase = (i * 4 + wave) * 16;
      gll16(A + (long long)(m_blk + rbase + arow) * 1024 + kt + akc, &As[rbase * 32]);
      gll16(B + (long long)(n_blk + rbase + arow) * 1024 + kt + akc, &Bs[rbase * 32]);
    }
    __syncthreads();
    bf16x8 af[4], bfr[4];
    #pragma unroll
    for (int mi = 0; mi < 4; ++mi)
      af[mi] = *(const bf16x8*)&As[(wm + mi * 16 + c) * 32 + (g << 3)];
    #pragma unroll
    for (int ni = 0; ni < 4; ++ni)
      bfr[ni] = *(const bf16x8*)&Bs[(wn + ni * 16 + c) * 32 + (g << 3)];
    #pragma unroll
    for (int mi = 0; mi < 4; ++mi)
      #pragma unroll
      for (int ni = 0; ni < 4; ++ni)
        acc[mi][ni] = __builtin_amdgcn_mfma_f32_16x16x32_bf16(af[mi], bfr[ni], acc[mi][ni], 0, 0, 0);
    __syncthreads();
  }
  int col_base = n_blk + wn;   // 64-aligned; never straddles q/k/v/gate boundaries
  if (col_base < 2048) {
    // q or k: per-(row,head) RMSNorm; head == this wave's 64-col span
    int isk = col_base >= 1024;
    float scale = isk ? 1.0f : (0.125f * LOG2E);
    const float* nw = isk ? kw : qw;
    float w[4];
    #pragma unroll
    for (int ni = 0; ni < 4; ++ni) w[ni] = nw[ni * 16 + c];
    #pragma unroll
    for (int mi = 0; mi < 4; ++mi)
      #pragma unroll
      for (int r = 0; r < 4; ++r) {
        float ss = 0.f;
        #pragma unroll
        for (int ni = 0; ni < 4; ++ni) ss += acc[mi][ni][r] * acc[mi][ni][r];
        #pragma unroll
        for (int off = 8; off > 0; off >>= 1) ss += __shfl_xor(ss, off);
        float inv = rsqrtf(ss * (1.0f / 64.0f) + EPS) * scale;
        int row = m_blk + wm + mi * 16 + g * 4 + r;
        #pragma unroll
        for (int ni = 0; ni < 4; ++ni)
          C[(long long)row * QKS + col_base + ni * 16 + c] = f2bf(acc[mi][ni][r] * inv * w[ni]);
      }
  } else if (col_base < 3072) {
    // v: plain store
    #pragma unroll
    for (int mi = 0; mi < 4; ++mi)
      #pragma unroll
      for (int r = 0; r < 4; ++r) {
        int row = m_blk + wm + mi * 16 + g * 4 + r;
        #pragma unroll
        for (int ni = 0; ni < 4; ++ni)
          C[(long long)row * QKS + col_base + ni * 16 + c] = f2bf(acc[mi][ni][r]);
      }
  } else if (col_base == 3072) {
    // gate: ni==0 cols 3072..3087 -> sigmoid -> fp32 gate[row][c]
    #pragma unroll
    for (int mi = 0; mi < 4; ++mi)
      #pragma unroll
      for (int r = 0; r < 4; ++r) {
        int row = m_blk + wm + mi * 16 + g * 4 + r;
        float v = acc[mi][0][r];
        gate[(long long)row * 16 + c] = 1.0f / (1.0f + EXP2(-v * LOG2E));
      }
  }
  // col_base == 3136: pad, skip
}

// ---------- 3. generic tiled GEMM (o-proj): C=A@B^T (+res), dtype-dispatched ----------
__global__ void gemm_tiled(const ushort_t* __restrict__ A, const ushort_t* __restrict__ B,
                           void* __restrict__ Cv, const void* __restrict__ res,
                           const int* __restrict__ flag,
                           int K, int lda, int ldb, int ldc) {
  __shared__ ushort_t As[128 * 32];
  __shared__ ushort_t Bs[128 * 32];
  int tid = threadIdx.x, wave = tid >> 6, lane = tid & 63;
  int m_blk = blockIdx.y * 128, n_blk = blockIdx.x * 128;
  int wm = (wave & 1) * 64, wn = (wave >> 1) * 64;
  int g = lane >> 4, c = lane & 15;
  int arow = lane >> 2;
  int akc = (lane & 3) << 3;
  f32x4 acc[4][4] = {};
  for (int kt = 0; kt < K; kt += 32) {
    #pragma unroll
    for (int i = 0; i < 2; ++i) {
      int rbase = (i * 4 + wave) * 16;
      gll16(A + (long long)(m_blk + rbase + arow) * lda + kt + akc, &As[rbase * 32]);
      gll16(B + (long long)(n_blk + rbase + arow) * ldb + kt + akc, &Bs[rbase * 32]);
    }
    __syncthreads();
    bf16x8 af[4], bfr[4];
    #pragma unroll
    for (int mi = 0; mi < 4; ++mi)
      af[mi] = *(const bf16x8*)&As[(wm + mi * 16 + c) * 32 + (g << 3)];
    #pragma unroll
    for (int ni = 0; ni < 4; ++ni)
      bfr[ni] = *(const bf16x8*)&Bs[(wn + ni * 16 + c) * 32 + (g << 3)];
    #pragma unroll
    for (int mi = 0; mi < 4; ++mi)
      #pragma unroll
      for (int ni = 0; ni < 4; ++ni)
        acc[mi][ni] = __builtin_amdgcn_mfma_f32_16x16x32_bf16(af[mi], bfr[ni], acc[mi][ni], 0, 0, 0);
    __syncthreads();
  }
  int outbf = flag ? *flag : 1;
  #pragma unroll
  for (int mi = 0; mi < 4; ++mi)
    #pragma unroll
    for (int ni = 0; ni < 4; ++ni)
      #pragma unroll
      for (int r = 0; r < 4; ++r) {
        int row = m_blk + wm + mi * 16 + g * 4 + r;
        int col = n_blk + wn + ni * 16 + c;
        long long idx = (long long)row * ldc + col;
        float v = acc[mi][ni][r];
        if (res) v += outbf ? bf2f(((const ushort_t*)res)[idx]) : ((const float*)res)[idx];
        if (outbf) ((ushort_t*)Cv)[idx] = f2bf(v);
        else       ((float*)Cv)[idx] = v;
      }
}

// ---------- 4. V transpose (bf16): Vt[bh][d][s] = qkv2[b*S+s][2048+h*64+d] ----------
__global__ void vt_kernel(const ushort_t* __restrict__ qkv, ushort_t* __restrict__ Vt) {
  __shared__ ushort_t tile[64][65];
  int s0 = blockIdx.x * 64;
  int bh = blockIdx.y;
  int b = bh >> 4, h = bh & 15;
  const ushort_t* src = qkv + (long long)b * SEQ * QKS + 2048 + h * 64;
  int d = threadIdx.x & 63, srow = threadIdx.x >> 6;
  #pragma unroll
  for (int i = 0; i < 16; ++i) {
    int sl = i * 4 + srow;
    tile[sl][d] = src[(long long)(s0 + sl) * QKS + d];
  }
  __syncthreads();
  ushort_t* dst = Vt + (long long)bh * 64 * SEQ + s0;
  int sl2 = threadIdx.x & 63, drow = threadIdx.x >> 6;
  #pragma unroll
  for (int i = 0; i < 16; ++i) {
    int dd = i * 4 + drow;
    dst[(long long)dd * SEQ + sl2] = tile[sl2][dd];
  }
}

// ---------- 5. flash attention: stride-72 LDS (exact 27648 B), reg prefetch ----------
__global__ void flash_kernel(const ushort_t* __restrict__ qkv, const ushort_t* __restrict__ Vt,
                             const float* __restrict__ gate, ushort_t* __restrict__ ao) {
  __shared__ ushort_t smem[192 * KST];   // Ks 64*KST | Vs 64*KST | Ps 4 waves x 16*KST
  ushort_t* Ks = smem;
  ushort_t* Vs = smem + 64 * KST;
  int tid = threadIdx.x, wave = tid >> 6, lane = tid & 63;
  ushort_t* Ps = smem + 128 * KST + wave * (16 * KST);
  int g = lane >> 4, c = lane & 15;
  int q0 = blockIdx.x * 64;
  int bh = blockIdx.y, b = bh >> 4, h = bh & 15;
  const ushort_t* qbase = qkv + (long long)b * SEQ * QKS + h * 64;
  const ushort_t* kbase = qbase + 1024;
  const ushort_t* vtbase = Vt + (long long)bh * 64 * SEQ;
  int qrow = q0 + wave * 16 + c;
  bf16x8 qa0 = *(const bf16x8*)(qbase + (long long)qrow * QKS + (g << 3));
  bf16x8 qa1 = *(const bf16x8*)(qbase + (long long)qrow * QKS + 32 + (g << 3));
  f32x4 accO[4] = {};
  float m_i[4] = {-1e30f, -1e30f, -1e30f, -1e30f};
  float l_i[4] = {0.f, 0.f, 0.f, 0.f};
  int srow = tid >> 3;            // 0..31
  int sch = (tid & 7) << 3;       // element col 0,8,..,56
  uint4 pk[2], pv[2];
  #pragma unroll
  for (int t = 0; t < 2; ++t) {
    int row = t * 32 + srow;
    pk[t] = *(const uint4*)(kbase + (long long)row * QKS + sch);
    pv[t] = *(const uint4*)(vtbase + (long long)row * SEQ + sch);
  }
  for (int s0 = 0; s0 < SEQ; s0 += 64) {
    #pragma unroll
    for (int t = 0; t < 2; ++t) {
      int row = t * 32 + srow;
      *(uint4*)&Ks[row * KST + sch] = pk[t];
      *(uint4*)&Vs[row * KST + sch] = pv[t];
    }
    if (s0 + 64 < SEQ) {
      #pragma unroll
      for (int t = 0; t < 2; ++t) {
        int row = t * 32 + srow;
        pk[t] = *(const uint4*)(kbase + (long long)(s0 + 64 + row) * QKS + sch);
        pv[t] = *(const uint4*)(vtbase + (long long)row * SEQ + s0 + 64 + sch);
      }
    }
    __syncthreads();
    f32x4 sacc[4] = {};
    #pragma unroll
    for (int ni = 0; ni < 4; ++ni) {
      bf16x8 kb0 = *(const bf16x8*)&Ks[(ni * 16 + c) * KST + (g << 3)];
      bf16x8 kb1 = *(const bf16x8*)&Ks[(ni * 16 + c) * KST + 32 + (g << 3)];
      sacc[ni] = __builtin_amdgcn_mfma_f32_16x16x32_bf16(qa0, kb0, sacc[ni], 0, 0, 0);
      sacc[ni] = __builtin_amdgcn_mfma_f32_16x16x32_bf16(qa1, kb1, sacc[ni], 0, 0, 0);
    }
    float alpha[4];
    #pragma unroll
    for (int r = 0; r < 4; ++r) {
      float mx = fmaxf(fmaxf(sacc[0][r], sacc[1][r]), fmaxf(sacc[2][r], sacc[3][r]));
      #pragma unroll
      for (int off = 8; off > 0; off >>= 1) mx = fmaxf(mx, __shfl_xor(mx, off));
      float mn = fmaxf(m_i[r], mx);
      alpha[r] = EXP2(m_i[r] - mn);
      m_i[r] = mn;
      float rs = 0.f;
      #pragma unroll
      for (int ni = 0; ni < 4; ++ni) {
        float p = EXP2(sacc[ni][r] - mn);
        rs += p;
        Ps[(g * 4 + r) * KST + ni * 16 + c] = f2bf(p);
      }
      #pragma unroll
      for (int off = 8; off > 0; off >>= 1) rs += __shfl_xor(rs, off);
      l_i[r] = l_i[r] * alpha[r] + rs;
    }
    #pragma unroll
    for (int di = 0; di < 4; ++di)
      #pragma unroll
      for (int r = 0; r < 4; ++r) accO[di][r] *= alpha[r];
    bf16x8 pa0 = *(const bf16x8*)&Ps[c * KST + (g << 3)];
    bf16x8 pa1 = *(const bf16x8*)&Ps[c * KST + 32 + (g << 3)];
    #pragma unroll
    for (int di = 0; di < 4; ++di) {
      bf16x8 vb0 = *(const bf16x8*)&Vs[(di * 16 + c) * KST + (g << 3)];
      bf16x8 vb1 = *(const bf16x8*)&Vs[(di * 16 + c) * KST + 32 + (g << 3)];
      accO[di] = __builtin_amdgcn_mfma_f32_16x16x32_bf16(pa0, vb0, accO[di], 0, 0, 0);
      accO[di] = __builtin_amdgcn_mfma_f32_16x16x32_bf16(pa1, vb1, accO[di], 0, 0, 0);
    }
    __syncthreads();
  }
  #pragma unroll
  for (int r = 0; r < 4; ++r) {
    int row = q0 + wave * 16 + g * 4 + r;
    float sg = gate[(long long)(b * SEQ + row) * 16 + h];  // pre-sigmoided
    float scale = sg / l_i[r];
    #pragma unroll
    for (int di = 0; di < 4; ++di) {
      int col = h * 64 + di * 16 + c;
      ao[(long long)(b * SEQ + row) * 1024 + col] = f2bf(accO[di][r] * scale);
    }
  }
}

extern "C" void kernel_launch(void* const* d_in, const int* in_sizes, int n_in,
                              void* d_out, int out_size, void* d_ws, size_t ws_size,
                              hipStream_t stream) {
  (void)in_sizes; (void)n_in; (void)out_size; (void)ws_size;
  char* ws = (char*)d_ws;
  ushort_t* Wcat = (ushort_t*)(ws);                             // 7 MB: 3200x1024 bf16 (qkvw|gw|pad)
  ushort_t* ow   = (ushort_t*)(ws + (7ll << 20));               // 2 MB bf16 1024x1024
  float*    pwf  = (float*)   (ws + (9ll << 20));               // 4 KB
  float*    qnf  = (float*)   (ws + (9ll << 20) + (8 << 10));
  float*    knf  = (float*)   (ws + (9ll << 20) + (12 << 10));
  int*      flag = (int*)     (ws + (9ll << 20) + (16 << 10));
  float*    gate = (float*)   (ws + (9ll << 20) + (64 << 10));  // 256 KB fp32 (sigmoided)
  ushort_t* xn   = (ushort_t*)(ws + (10ll << 20));              // 8 MB bf16 4096x1024
  ushort_t* qkv2 = (ushort_t*)(ws + (18ll << 20));              // 26 MB bf16 4096x3200
  ushort_t* Vt   = (ushort_t*)(ws + (44ll << 20));              // 8 MB bf16 32x64x2048
  ushort_t* ao   = (ushort_t*)(ws + (52ll << 20));              // 8 MB bf16 4096x1024

  // 0. detect + canonicalize weights
  detect_kernel<<<1, 256, 0, stream>>>((const unsigned int*)d_in[0], flag);
  conv_f32<<<4, 256, 0, stream>>>(d_in[1], pwf, 1024, flag);
  conv_b16<<<12288, 256, 0, stream>>>(d_in[2], Wcat, 3145728, flag);          // qkv_w -> rows 0..3071
  conv_b16<<<64, 256, 0, stream>>>(d_in[3], Wcat + 3072 * 1024, 16384, flag); // gate_w -> rows 3072..3087
  conv_b16<<<4096, 256, 0, stream>>>(d_in[4], ow, 1048576, flag);
  conv_f32<<<1, 256, 0, stream>>>(d_in[5], qnf, 64, flag);
  conv_f32<<<1, 256, 0, stream>>>(d_in[6], knf, 64, flag);

  // 1. prenorm (raw x -> bf16 xn)
  prenorm_kernel<<<MROWS, 256, 0, stream>>>(d_in[0], pwf, xn, flag);
  // 2. fused qkv+gate GEMM with qk-norm / sigmoid epilogue (N=3200 incl. pad tile)
  gemm_qkv_fused<<<dim3(25, 32), 256, 0, stream>>>(xn, Wcat, qkv2, gate, qnf, knf);
  // 3. V transpose
  vt_kernel<<<dim3(32, 32), 256, 0, stream>>>(qkv2, Vt);
  // 4. flash attention (fused gate multiply)
  flash_kernel<<<dim3(32, 32), 256, 0, stream>>>(qkv2, Vt, gate, ao);
  // 5. out = ao @ o_w^T + x (raw residual), dtype-dispatched store
  gemm_tiled<<<dim3(8, 32), 256, 0, stream>>>(ao, ow, d_out, d_in[0], flag,
                                              1024, 1024, 1024, 1024);
}

// Round 7
// 365.042 us; speedup vs baseline: 1.1983x; 1.1660x over previous
//
#include <hip/hip_runtime.h>
#include <math.h>

typedef __bf16 bf16x8 __attribute__((ext_vector_type(8)));
typedef float f32x4 __attribute__((ext_vector_type(4)));
typedef unsigned short ushort_t;

#define SEQ 2048
#define MROWS 4096          // B*S
#define EPS 1e-5f
#define QKS 3200            // fused qkv output row stride (q 0..1023, k 1024.., v 2048.., gate 3072..3087, pad)
#define LOG2E 1.4426950408889634f

#if __has_builtin(__builtin_amdgcn_exp2f)
#define EXP2(x) __builtin_amdgcn_exp2f(x)
#else
#define EXP2(x) exp2f(x)
#endif

// ---------- bf16 helpers ----------
__device__ __forceinline__ float bf2f(ushort_t u) {
  union { unsigned int i; float f; } c; c.i = ((unsigned int)u) << 16; return c.f;
}
__device__ __forceinline__ ushort_t f2bf(float f) {
  __bf16 h = (__bf16)f;
  union { __bf16 b; ushort_t u; } c; c.b = h; return c.u;
}
__device__ __forceinline__ unsigned int pack_bf(float a, float b) {
  return (unsigned int)f2bf(a) | ((unsigned int)f2bf(b) << 16);
}

// ---------- reductions ----------
__device__ __forceinline__ float wave_sum(float v) {
  #pragma unroll
  for (int off = 32; off > 0; off >>= 1) v += __shfl_xor(v, off);
  return v;
}

// ---------- 0a. dtype detector: is x bf16 (1) or fp32 (0)? ----------
__global__ void detect_kernel(const unsigned int* __restrict__ xraw, int* __restrict__ flag) {
  int tid = threadIdx.x;
  int cnt = 0;
  for (int i = tid; i < 4096; i += 256) {
    unsigned int e = (xraw[i] >> 7) & 0xFFu;
    cnt += (e >= 100u && e <= 150u) ? 1 : 0;
  }
  __shared__ int sred[256];
  sred[tid] = cnt;
  __syncthreads();
  for (int s = 128; s > 0; s >>= 1) {
    if (tid < s) sred[tid] += sred[tid + s];
    __syncthreads();
  }
  if (tid == 0) flag[0] = (sred[0] > 2048) ? 1 : 0;
}

// ---------- 0b. canonicalize ----------
__global__ void conv_f32(const void* __restrict__ in, float* __restrict__ outp,
                         int n, const int* __restrict__ flag) {
  int i = blockIdx.x * 256 + threadIdx.x;
  if (i >= n) return;
  if (*flag) outp[i] = bf2f(((const ushort_t*)in)[i]);
  else       outp[i] = ((const float*)in)[i];
}
__global__ void conv_b16(const void* __restrict__ in, ushort_t* __restrict__ outp,
                         int n, const int* __restrict__ flag) {
  int i = blockIdx.x * 256 + threadIdx.x;
  if (i >= n) return;
  if (*flag) outp[i] = ((const ushort_t*)in)[i];
  else       outp[i] = f2bf(((const float*)in)[i]);
}

// ---------- 1. prenorm RMSNorm (raw x per flag -> bf16 xn) ----------
__global__ void prenorm_kernel(const void* __restrict__ xraw,
                               const float* __restrict__ w,
                               ushort_t* __restrict__ xn,
                               const int* __restrict__ flag) {
  int row = blockIdx.x;
  int tid = threadIdx.x;
  float4 u;
  if (*flag) {
    ushort4 s = ((const ushort4*)xraw)[row * 256 + tid];
    u.x = bf2f(s.x); u.y = bf2f(s.y); u.z = bf2f(s.z); u.w = bf2f(s.w);
  } else {
    u = ((const float4*)xraw)[row * 256 + tid];
  }
  float ss = u.x*u.x + u.y*u.y + u.z*u.z + u.w*u.w;
  ss = wave_sum(ss);
  __shared__ float red[4];
  if ((tid & 63) == 0) red[tid >> 6] = ss;
  __syncthreads();
  float total = red[0] + red[1] + red[2] + red[3];
  float inv = rsqrtf(total * (1.0f / 1024.0f) + EPS);
  float4 wu = ((const float4*)w)[tid];
  ushort4 o;
  o.x = f2bf(u.x * inv * wu.x);
  o.y = f2bf(u.y * inv * wu.y);
  o.z = f2bf(u.z * inv * wu.z);
  o.w = f2bf(u.w * inv * wu.w);
  ((ushort4*)(xn + (long long)row * 1024))[tid] = o;
}

// ---------- async global->LDS 16B ----------
__device__ __forceinline__ void gll16(const ushort_t* g, ushort_t* l) {
  __builtin_amdgcn_global_load_lds(
      (const __attribute__((address_space(1))) unsigned int*)g,
      (__attribute__((address_space(3))) unsigned int*)l, 16, 0, 0);
}

// ---------- 2. fused qkv+gate GEMM, 128x128 tile (m97 structure) ----------
__global__ void gemm_qkv_fused(const ushort_t* __restrict__ A, const ushort_t* __restrict__ B,
                               ushort_t* __restrict__ C, float* __restrict__ gate,
                               const float* __restrict__ qw, const float* __restrict__ kw) {
  __shared__ ushort_t As[128 * 32];
  __shared__ ushort_t Bs[128 * 32];
  int tid = threadIdx.x, wave = tid >> 6, lane = tid & 63;
  int m_blk = blockIdx.y * 128, n_blk = blockIdx.x * 128;
  int wm = (wave & 1) * 64, wn = (wave >> 1) * 64;
  int g = lane >> 4, c = lane & 15;
  int arow = lane >> 2;
  int akc = (lane & 3) << 3;
  f32x4 acc[4][4] = {};
  for (int kt = 0; kt < 1024; kt += 32) {
    #pragma unroll
    for (int i = 0; i < 2; ++i) {
      int rbase = (i * 4 + wave) * 16;
      gll16(A + (long long)(m_blk + rbase + arow) * 1024 + kt + akc, &As[rbase * 32]);
      gll16(B + (long long)(n_blk + rbase + arow) * 1024 + kt + akc, &Bs[rbase * 32]);
    }
    __syncthreads();
    bf16x8 af[4], bfr[4];
    #pragma unroll
    for (int mi = 0; mi < 4; ++mi)
      af[mi] = *(const bf16x8*)&As[(wm + mi * 16 + c) * 32 + (g << 3)];
    #pragma unroll
    for (int ni = 0; ni < 4; ++ni)
      bfr[ni] = *(const bf16x8*)&Bs[(wn + ni * 16 + c) * 32 + (g << 3)];
    #pragma unroll
    for (int mi = 0; mi < 4; ++mi)
      #pragma unroll
      for (int ni = 0; ni < 4; ++ni)
        acc[mi][ni] = __builtin_amdgcn_mfma_f32_16x16x32_bf16(af[mi], bfr[ni], acc[mi][ni], 0, 0, 0);
    __syncthreads();
  }
  int col_base = n_blk + wn;   // 64-aligned; never straddles q/k/v/gate boundaries
  if (col_base < 2048) {
    int isk = col_base >= 1024;
    float scale = isk ? 1.0f : (0.125f * LOG2E);
    const float* nw = isk ? kw : qw;
    float w[4];
    #pragma unroll
    for (int ni = 0; ni < 4; ++ni) w[ni] = nw[ni * 16 + c];
    #pragma unroll
    for (int mi = 0; mi < 4; ++mi)
      #pragma unroll
      for (int r = 0; r < 4; ++r) {
        float ss = 0.f;
        #pragma unroll
        for (int ni = 0; ni < 4; ++ni) ss += acc[mi][ni][r] * acc[mi][ni][r];
        #pragma unroll
        for (int off = 8; off > 0; off >>= 1) ss += __shfl_xor(ss, off);
        float inv = rsqrtf(ss * (1.0f / 64.0f) + EPS) * scale;
        int row = m_blk + wm + mi * 16 + g * 4 + r;
        #pragma unroll
        for (int ni = 0; ni < 4; ++ni)
          C[(long long)row * QKS + col_base + ni * 16 + c] = f2bf(acc[mi][ni][r] * inv * w[ni]);
      }
  } else if (col_base < 3072) {
    #pragma unroll
    for (int mi = 0; mi < 4; ++mi)
      #pragma unroll
      for (int r = 0; r < 4; ++r) {
        int row = m_blk + wm + mi * 16 + g * 4 + r;
        #pragma unroll
        for (int ni = 0; ni < 4; ++ni)
          C[(long long)row * QKS + col_base + ni * 16 + c] = f2bf(acc[mi][ni][r]);
      }
  } else if (col_base == 3072) {
    #pragma unroll
    for (int mi = 0; mi < 4; ++mi)
      #pragma unroll
      for (int r = 0; r < 4; ++r) {
        int row = m_blk + wm + mi * 16 + g * 4 + r;
        float v = acc[mi][0][r];
        gate[(long long)row * 16 + c] = 1.0f / (1.0f + EXP2(-v * LOG2E));
      }
  }
}

// ---------- 3. generic tiled GEMM (o-proj): C=A@B^T (+res), dtype-dispatched ----------
__global__ void gemm_tiled(const ushort_t* __restrict__ A, const ushort_t* __restrict__ B,
                           void* __restrict__ Cv, const void* __restrict__ res,
                           const int* __restrict__ flag,
                           int K, int lda, int ldb, int ldc) {
  __shared__ ushort_t As[128 * 32];
  __shared__ ushort_t Bs[128 * 32];
  int tid = threadIdx.x, wave = tid >> 6, lane = tid & 63;
  int m_blk = blockIdx.y * 128, n_blk = blockIdx.x * 128;
  int wm = (wave & 1) * 64, wn = (wave >> 1) * 64;
  int g = lane >> 4, c = lane & 15;
  int arow = lane >> 2;
  int akc = (lane & 3) << 3;
  f32x4 acc[4][4] = {};
  for (int kt = 0; kt < K; kt += 32) {
    #pragma unroll
    for (int i = 0; i < 2; ++i) {
      int rbase = (i * 4 + wave) * 16;
      gll16(A + (long long)(m_blk + rbase + arow) * lda + kt + akc, &As[rbase * 32]);
      gll16(B + (long long)(n_blk + rbase + arow) * ldb + kt + akc, &Bs[rbase * 32]);
    }
    __syncthreads();
    bf16x8 af[4], bfr[4];
    #pragma unroll
    for (int mi = 0; mi < 4; ++mi)
      af[mi] = *(const bf16x8*)&As[(wm + mi * 16 + c) * 32 + (g << 3)];
    #pragma unroll
    for (int ni = 0; ni < 4; ++ni)
      bfr[ni] = *(const bf16x8*)&Bs[(wn + ni * 16 + c) * 32 + (g << 3)];
    #pragma unroll
    for (int mi = 0; mi < 4; ++mi)
      #pragma unroll
      for (int ni = 0; ni < 4; ++ni)
        acc[mi][ni] = __builtin_amdgcn_mfma_f32_16x16x32_bf16(af[mi], bfr[ni], acc[mi][ni], 0, 0, 0);
    __syncthreads();
  }
  int outbf = flag ? *flag : 1;
  #pragma unroll
  for (int mi = 0; mi < 4; ++mi)
    #pragma unroll
    for (int ni = 0; ni < 4; ++ni)
      #pragma unroll
      for (int r = 0; r < 4; ++r) {
        int row = m_blk + wm + mi * 16 + g * 4 + r;
        int col = n_blk + wn + ni * 16 + c;
        long long idx = (long long)row * ldc + col;
        float v = acc[mi][ni][r];
        if (res) v += outbf ? bf2f(((const ushort_t*)res)[idx]) : ((const float*)res)[idx];
        if (outbf) ((ushort_t*)Cv)[idx] = f2bf(v);
        else       ((float*)Cv)[idx] = v;
      }
}

// ---------- 4. V transpose (bf16): Vt[bh][d][s] = qkv2[b*S+s][2048+h*64+d] ----------
__global__ void vt_kernel(const ushort_t* __restrict__ qkv, ushort_t* __restrict__ Vt) {
  __shared__ ushort_t tile[64][65];
  int s0 = blockIdx.x * 64;
  int bh = blockIdx.y;
  int b = bh >> 4, h = bh & 15;
  const ushort_t* src = qkv + (long long)b * SEQ * QKS + 2048 + h * 64;
  int d = threadIdx.x & 63, srow = threadIdx.x >> 6;
  #pragma unroll
  for (int i = 0; i < 16; ++i) {
    int sl = i * 4 + srow;
    tile[sl][d] = src[(long long)(s0 + sl) * QKS + d];
  }
  __syncthreads();
  ushort_t* dst = Vt + (long long)bh * 64 * SEQ + s0;
  int sl2 = threadIdx.x & 63, drow = threadIdx.x >> 6;
  #pragma unroll
  for (int i = 0; i < 16; ++i) {
    int dd = i * 4 + drow;
    dst[(long long)dd * SEQ + sl2] = tile[sl2][dd];
  }
}

// ---------- 5. flash attention: stride-64 XOR-swizzled K/V, P via lane shuffles ----------
// grid (SEQ/64, 32). Computes S^T (mfma operand swap) so softmax state is per-lane;
// accumulates O^T; 16B chunk ch of LDS row r lives at ch^(r&7)  -> conflict-free.
__global__ void flash_kernel(const ushort_t* __restrict__ qkv, const ushort_t* __restrict__ Vt,
                             const float* __restrict__ gate, ushort_t* __restrict__ ao) {
  __shared__ ushort_t Ks[64 * 64];
  __shared__ ushort_t Vs[64 * 64];
  int tid = threadIdx.x, wave = tid >> 6, lane = tid & 63;
  int g = lane >> 4, c = lane & 15;
  int q0 = blockIdx.x * 64;
  int bh = blockIdx.y, b = bh >> 4, h = bh & 15;
  const ushort_t* qbase = qkv + (long long)b * SEQ * QKS + h * 64;
  const ushort_t* kbase = qbase + 1024;
  const ushort_t* vtbase = Vt + (long long)bh * 64 * SEQ;
  int qrow = q0 + wave * 16 + c;
  bf16x8 qa0 = *(const bf16x8*)(qbase + (long long)qrow * QKS + (g << 3));
  bf16x8 qa1 = *(const bf16x8*)(qbase + (long long)qrow * QKS + 32 + (g << 3));
  f32x4 accO[4] = {};
  float m_i = -1e30f, l_i = 0.f;
  int srow = tid >> 3;            // 0..31 (two t-iters: +32)
  int schk = tid & 7;             // 16B chunk index 0..7
  uint4 pk[2], pv[2];
  #pragma unroll
  for (int t = 0; t < 2; ++t) {
    int row = t * 32 + srow;
    pk[t] = *(const uint4*)(kbase + (long long)row * QKS + (schk << 3));
    pv[t] = *(const uint4*)(vtbase + (long long)row * SEQ + (schk << 3));
  }
  for (int s0 = 0; s0 < SEQ; s0 += 64) {
    #pragma unroll
    for (int t = 0; t < 2; ++t) {
      int row = t * 32 + srow;
      int sc = (schk ^ (row & 7)) << 3;     // swizzled chunk
      *(uint4*)&Ks[row * 64 + sc] = pk[t];
      *(uint4*)&Vs[row * 64 + sc] = pv[t];
    }
    if (s0 + 64 < SEQ) {
      #pragma unroll
      for (int t = 0; t < 2; ++t) {
        int row = t * 32 + srow;
        pk[t] = *(const uint4*)(kbase + (long long)(s0 + 64 + row) * QKS + (schk << 3));
        pv[t] = *(const uint4*)(vtbase + (long long)row * SEQ + s0 + 64 + (schk << 3));
      }
    }
    __syncthreads();
    // S^T = K . Q^T : sacc[ni][r] = S[qrow=c][s = 16ni + 4g + r]
    f32x4 sacc[4] = {};
    #pragma unroll
    for (int ni = 0; ni < 4; ++ni) {
      int n = ni * 16 + c;
      bf16x8 kb0 = *(const bf16x8*)&Ks[n * 64 + ((g ^ (n & 7)) << 3)];
      bf16x8 kb1 = *(const bf16x8*)&Ks[n * 64 + (((4 + g) ^ (n & 7)) << 3)];
      sacc[ni] = __builtin_amdgcn_mfma_f32_16x16x32_bf16(kb0, qa0, sacc[ni], 0, 0, 0);
      sacc[ni] = __builtin_amdgcn_mfma_f32_16x16x32_bf16(kb1, qa1, sacc[ni], 0, 0, 0);
    }
    // per-lane online softmax (base 2) for qrow=c over 16 scores; combine across g-copies
    float mx = fmaxf(fmaxf(fmaxf(sacc[0][0], sacc[0][1]), fmaxf(sacc[0][2], sacc[0][3])),
                     fmaxf(fmaxf(sacc[1][0], sacc[1][1]), fmaxf(sacc[1][2], sacc[1][3])));
    mx = fmaxf(mx, fmaxf(fmaxf(fmaxf(sacc[2][0], sacc[2][1]), fmaxf(sacc[2][2], sacc[2][3])),
                         fmaxf(fmaxf(sacc[3][0], sacc[3][1]), fmaxf(sacc[3][2], sacc[3][3]))));
    mx = fmaxf(mx, __shfl_xor(mx, 16));
    mx = fmaxf(mx, __shfl_xor(mx, 32));
    float mn = fmaxf(m_i, mx);
    float alpha = EXP2(m_i - mn);
    m_i = mn;
    float rs = 0.f;
    unsigned int u[4][2];
    #pragma unroll
    for (int ni = 0; ni < 4; ++ni) {
      float p0 = EXP2(sacc[ni][0] - mn);
      float p1 = EXP2(sacc[ni][1] - mn);
      float p2 = EXP2(sacc[ni][2] - mn);
      float p3 = EXP2(sacc[ni][3] - mn);
      rs += (p0 + p1) + (p2 + p3);
      u[ni][0] = pack_bf(p0, p1);
      u[ni][1] = pack_bf(p2, p3);
    }
    rs += __shfl_xor(rs, 16);
    rs += __shfl_xor(rs, 32);
    l_i = l_i * alpha + rs;
    #pragma unroll
    for (int di = 0; di < 4; ++di)
      #pragma unroll
      for (int r = 0; r < 4; ++r) accO[di][r] *= alpha;
    // build P^T B-operand fragments: pb0 = P[c][8g+jj], pb1 = P[c][32+8g+jj]
    int src0 = (((2 * g) & 3) << 4) | c;
    int src1 = (((2 * g + 1) & 3) << 4) | c;
    int hi = g >> 1;
    union { bf16x8 v; unsigned int d[4]; } pb0, pb1;
    {
      unsigned int a0 = __shfl((int)u[0][0], src0), b0 = __shfl((int)u[1][0], src0);
      unsigned int a1 = __shfl((int)u[0][1], src0), b1 = __shfl((int)u[1][1], src0);
      unsigned int a2 = __shfl((int)u[0][0], src1), b2 = __shfl((int)u[1][0], src1);
      unsigned int a3 = __shfl((int)u[0][1], src1), b3 = __shfl((int)u[1][1], src1);
      pb0.d[0] = hi ? b0 : a0; pb0.d[1] = hi ? b1 : a1;
      pb0.d[2] = hi ? b2 : a2; pb0.d[3] = hi ? b3 : a3;
      a0 = __shfl((int)u[2][0], src0); b0 = __shfl((int)u[3][0], src0);
      a1 = __shfl((int)u[2][1], src0); b1 = __shfl((int)u[3][1], src0);
      a2 = __shfl((int)u[2][0], src1); b2 = __shfl((int)u[3][0], src1);
      a3 = __shfl((int)u[2][1], src1); b3 = __shfl((int)u[3][1], src1);
      pb1.d[0] = hi ? b0 : a0; pb1.d[1] = hi ? b1 : a1;
      pb1.d[2] = hi ? b2 : a2; pb1.d[3] = hi ? b3 : a3;
    }
    // O^T += V . P^T : accO[di][r] = O[qrow=c][d = 16di + 4g + r]
    #pragma unroll
    for (int di = 0; di < 4; ++di) {
      int n = di * 16 + c;
      bf16x8 vb0 = *(const bf16x8*)&Vs[n * 64 + ((g ^ (n & 7)) << 3)];
      bf16x8 vb1 = *(const bf16x8*)&Vs[n * 64 + (((4 + g) ^ (n & 7)) << 3)];
      accO[di] = __builtin_amdgcn_mfma_f32_16x16x32_bf16(vb0, pb0.v, accO[di], 0, 0, 0);
      accO[di] = __builtin_amdgcn_mfma_f32_16x16x32_bf16(vb1, pb1.v, accO[di], 0, 0, 0);
    }
    __syncthreads();
  }
  // epilogue: O * sigmoid(gate) / l -> ao[qrow][h*64+d], 8B packed stores
  long long rowg = (long long)(b * SEQ + q0 + wave * 16 + c);
  float sg = gate[rowg * 16 + h];              // pre-sigmoided
  float scale = sg / l_i;
  #pragma unroll
  for (int di = 0; di < 4; ++di) {
    ushort4 o;
    o.x = f2bf(accO[di][0] * scale);
    o.y = f2bf(accO[di][1] * scale);
    o.z = f2bf(accO[di][2] * scale);
    o.w = f2bf(accO[di][3] * scale);
    *(ushort4*)&ao[rowg * 1024 + h * 64 + di * 16 + g * 4] = o;
  }
}

extern "C" void kernel_launch(void* const* d_in, const int* in_sizes, int n_in,
                              void* d_out, int out_size, void* d_ws, size_t ws_size,
                              hipStream_t stream) {
  (void)in_sizes; (void)n_in; (void)out_size; (void)ws_size;
  char* ws = (char*)d_ws;
  ushort_t* Wcat = (ushort_t*)(ws);                             // 7 MB: 3200x1024 bf16 (qkvw|gw|pad)
  ushort_t* ow   = (ushort_t*)(ws + (7ll << 20));               // 2 MB bf16 1024x1024
  float*    pwf  = (float*)   (ws + (9ll << 20));               // 4 KB
  float*    qnf  = (float*)   (ws + (9ll << 20) + (8 << 10));
  float*    knf  = (float*)   (ws + (9ll << 20) + (12 << 10));
  int*      flag = (int*)     (ws + (9ll << 20) + (16 << 10));
  float*    gate = (float*)   (ws + (9ll << 20) + (64 << 10));  // 256 KB fp32 (sigmoided)
  ushort_t* xn   = (ushort_t*)(ws + (10ll << 20));              // 8 MB bf16 4096x1024
  ushort_t* qkv2 = (ushort_t*)(ws + (18ll << 20));              // 26 MB bf16 4096x3200
  ushort_t* Vt   = (ushort_t*)(ws + (44ll << 20));              // 8 MB bf16 32x64x2048
  ushort_t* ao   = (ushort_t*)(ws + (52ll << 20));              // 8 MB bf16 4096x1024

  // 0. detect + canonicalize weights
  detect_kernel<<<1, 256, 0, stream>>>((const unsigned int*)d_in[0], flag);
  conv_f32<<<4, 256, 0, stream>>>(d_in[1], pwf, 1024, flag);
  conv_b16<<<12288, 256, 0, stream>>>(d_in[2], Wcat, 3145728, flag);          // qkv_w -> rows 0..3071
  conv_b16<<<64, 256, 0, stream>>>(d_in[3], Wcat + 3072 * 1024, 16384, flag); // gate_w -> rows 3072..3087
  conv_b16<<<4096, 256, 0, stream>>>(d_in[4], ow, 1048576, flag);
  conv_f32<<<1, 256, 0, stream>>>(d_in[5], qnf, 64, flag);
  conv_f32<<<1, 256, 0, stream>>>(d_in[6], knf, 64, flag);

  // 1. prenorm (raw x -> bf16 xn)
  prenorm_kernel<<<MROWS, 256, 0, stream>>>(d_in[0], pwf, xn, flag);
  // 2. fused qkv+gate GEMM with qk-norm / sigmoid epilogue (N=3200 incl. pad tile)
  gemm_qkv_fused<<<dim3(25, 32), 256, 0, stream>>>(xn, Wcat, qkv2, gate, qnf, knf);
  // 3. V transpose
  vt_kernel<<<dim3(32, 32), 256, 0, stream>>>(qkv2, Vt);
  // 4. flash attention (fused gate multiply)
  flash_kernel<<<dim3(32, 32), 256, 0, stream>>>(qkv2, Vt, gate, ao);
  // 5. out = ao @ o_w^T + x (raw residual), dtype-dispatched store
  gemm_tiled<<<dim3(8, 32), 256, 0, stream>>>(ao, ow, d_out, d_in[0], flag,
                                              1024, 1024, 1024, 1024);
}